// Round 1
// baseline (1572.410 us; speedup 1.0000x reference)
//
#include <hip/hip_runtime.h>

// Problem constants
#define N_NODES 2048
#define N_EDGES 65536
#define BATCH   4
#define PPIX    4096   // H*W
#define STEPS   4

typedef __attribute__((ext_vector_type(4))) float f32x4;
typedef __attribute__((ext_vector_type(8))) short s16x8;

__device__ __forceinline__ unsigned short f2bf(float f) {
    unsigned u = __float_as_uint(f);
    unsigned r = u + 0x7fffu + ((u >> 16) & 1u);
    return (unsigned short)(r >> 16);
}
__device__ __forceinline__ float bf2f(unsigned short h) {
    return __uint_as_float(((unsigned)h) << 16);
}

// ---------------- weight conversion (fp32 -> bf16, mn_w zero-padded K 272->288)
__global__ void k_wconv(const float* __restrict__ w1, const float* __restrict__ w2,
                        const float* __restrict__ w3,
                        unsigned short* __restrict__ o1, unsigned short* __restrict__ o2,
                        unsigned short* __restrict__ o3) {
    int i = blockIdx.x * 256 + threadIdx.x;
    if (i < 256 * 416) o1[i] = f2bf(w1[i]);
    if (i < 128 * 256) o2[i] = f2bf(w2[i]);
    if (i < 128 * 288) {
        int r = i / 288, c = i - r * 288;
        o3[i] = (c < 272) ? f2bf(w3[r * 272 + c]) : (unsigned short)0;
    }
}

// ---------------- node encoder: relu(x @ ne_w.T + ne_b) -> (2048,128) fp32
__global__ __launch_bounds__(128) void k_node_enc(const float* __restrict__ x,
                                                  const float* __restrict__ w,
                                                  const float* __restrict__ b,
                                                  float* __restrict__ out) {
    __shared__ float xs[256];
    const int n = blockIdx.x;
    for (int i = threadIdx.x; i < 256; i += 128) xs[i] = x[n * 256 + i];
    __syncthreads();
    const int d = threadIdx.x;
    const float* wr = w + d * 256;
    float acc = b[d];
#pragma unroll 8
    for (int c = 0; c < 256; c++) acc += xs[c] * wr[c];
    out[n * 128 + d] = fmaxf(acc, 0.f);
}

// ---------------- edge encoder: relu(edge_attr @ ee_w.T + ee_b) -> (65536,128) bf16
__global__ __launch_bounds__(256) void k_edge_enc(const float* __restrict__ ea,
                                                  const float* __restrict__ w,
                                                  const float* __restrict__ b,
                                                  unsigned short* __restrict__ ef) {
    __shared__ float ws[128 * 64];
    __shared__ float bs[128];
    for (int i = threadIdx.x; i < 128 * 64; i += 256) ws[i] = w[i];
    if (threadIdx.x < 128) bs[threadIdx.x] = b[threadIdx.x];
    __syncthreads();
    const int e = blockIdx.x * 256 + threadIdx.x;
    float xr[64];
#pragma unroll
    for (int c = 0; c < 64; c++) xr[c] = ea[(size_t)e * 64 + c];
    for (int d = 0; d < 128; d++) {
        float acc = bs[d];
        const float* wr = &ws[d * 64];
#pragma unroll
        for (int c = 0; c < 64; c++) acc += xr[c] * wr[c];
        ef[(size_t)e * 128 + d] = f2bf(fmaxf(acc, 0.f));
    }
}

// ---------------- queries/values: einsum('oc,bcp->bop') + bias
__global__ __launch_bounds__(256) void k_qv(const float* __restrict__ fm,
                                            const float* __restrict__ qw, const float* __restrict__ qb,
                                            const float* __restrict__ vw, const float* __restrict__ vb,
                                            float* __restrict__ q, float* __restrict__ v) {
    __shared__ float fs[32][256];
    const int b = blockIdx.x >> 4;
    const int pt = blockIdx.x & 15;
    for (int i = threadIdx.x; i < 32 * 256; i += 256) {
        int c = i >> 8, p = i & 255;
        fs[c][p] = fm[(size_t)b * 32 * PPIX + (size_t)c * PPIX + pt * 256 + p];
    }
    __syncthreads();
    const int p = threadIdx.x;
    for (int o = 0; o < 16; o++) {
        float qa = qb[o], va = vb[o];
#pragma unroll
        for (int c = 0; c < 32; c++) {
            float f = fs[c][p];
            qa += qw[o * 32 + c] * f;
            va += vw[o * 32 + c] * f;
        }
        size_t oidx = ((size_t)b * 16 + o) * PPIX + pt * 256 + p;
        q[oidx] = qa;
        v[oidx] = va;
    }
}

// ---------------- attention per node (fused k-proj, softmax over p, res, nf_bf16 pack)
__global__ __launch_bounds__(256) void k_attn(const float* __restrict__ nf,
                                              const float* __restrict__ qbuf,
                                              const float* __restrict__ vbuf,
                                              const float* __restrict__ key_w,
                                              const float* __restrict__ key_b,
                                              const int* __restrict__ batch_index,
                                              unsigned short* __restrict__ nf_bf) {
    __shared__ float xs[128];
    __shared__ float k16s[16];
    __shared__ float red[256];
    __shared__ float vr[256 * 17];
    const int n = blockIdx.x;
    const int t = threadIdx.x;
    if (t < 128) xs[t] = nf[n * 128 + t];
    __syncthreads();
    if (t < 16) {
        const float* wr = key_w + t * 128;
        float a = key_b[t];
        for (int c = 0; c < 128; c++) a += xs[c] * wr[c];
        k16s[t] = a;
    }
    __syncthreads();
    float kk[16];
#pragma unroll
    for (int a = 0; a < 16; a++) kk[a] = k16s[a];
    const int b = batch_index[n];
    const float* q = qbuf + (size_t)b * 16 * PPIX;
    const float* v = vbuf + (size_t)b * 16 * PPIX;

    float s[16];
    float mx = -1e30f;
    for (int i = 0; i < 16; i++) {
        int p = i * 256 + t;
        float acc = 0.f;
#pragma unroll
        for (int a = 0; a < 16; a++) acc += kk[a] * q[a * PPIX + p];
        s[i] = acc;
        mx = fmaxf(mx, acc);
    }
    red[t] = mx;
    __syncthreads();
    for (int off = 128; off > 0; off >>= 1) {
        if (t < off) red[t] = fmaxf(red[t], red[t + off]);
        __syncthreads();
    }
    mx = red[0];
    __syncthreads();

    float wsum = 0.f;
    float vacc[16];
#pragma unroll
    for (int a = 0; a < 16; a++) vacc[a] = 0.f;
    for (int i = 0; i < 16; i++) {
        int p = i * 256 + t;
        float w = __expf(s[i] - mx);
        wsum += w;
#pragma unroll
        for (int a = 0; a < 16; a++) vacc[a] += w * v[a * PPIX + p];
    }
    red[t] = wsum;
    __syncthreads();
    for (int off = 128; off > 0; off >>= 1) {
        if (t < off) red[t] += red[t + off];
        __syncthreads();
    }
    wsum = red[0];
    __syncthreads();

#pragma unroll
    for (int a = 0; a < 16; a++) vr[t * 17 + a] = vacc[a];
    __syncthreads();
    for (int off = 128; off > 0; off >>= 1) {
        if (t < off) {
#pragma unroll
            for (int a = 0; a < 16; a++) vr[t * 17 + a] += vr[(t + off) * 17 + a];
        }
        __syncthreads();
    }
    if (t < 128) nf_bf[n * 144 + t] = f2bf(xs[t]);
    if (t < 16) {
        float rv = vr[t] / wsum;
        nf_bf[n * 144 + 128 + t] = f2bf(rv);
    }
}

// ---------------- fused 3-layer edge MLP + message scatter (bf16 MFMA)
// tile = 32 edges, 256 threads (4 waves), waves split the N dimension.
__global__ __launch_bounds__(256) void k_mlp(const unsigned short* __restrict__ nf_bf,
                                             unsigned short* __restrict__ ef_buf,
                                             const unsigned short* __restrict__ w1b,
                                             const unsigned short* __restrict__ w2b,
                                             const unsigned short* __restrict__ w3b,
                                             const float* __restrict__ me_b1,
                                             const float* __restrict__ me_b2,
                                             const float* __restrict__ mn_b,
                                             const int* __restrict__ ei,
                                             float* __restrict__ node_acc) {
    __shared__ __attribute__((aligned(16))) unsigned short catA[32 * 424]; // [x_i 0:144 | x_j 144:288 | ef 288:416 | pad]
    __shared__ __attribute__((aligned(16))) unsigned short out1[32 * 264];
    __shared__ int tgt_s[32];
    const int tid = threadIdx.x;
    const int e0 = blockIdx.x * 32;
    const int* srcI = ei;
    const int* tgtI = ei + N_EDGES;
    if (tid < 32) tgt_s[tid] = tgtI[e0 + tid];
    // gather staging: 52 x 16B chunks per edge
    for (int c = tid; c < 32 * 52; c += 256) {
        int e = c / 52;
        int r = c - e * 52;
        const unsigned short* sp;
        int dcol;
        if (r < 18)      { sp = nf_bf + (size_t)tgtI[e0 + e] * 144 + r * 8;        dcol = r * 8; }
        else if (r < 36) { sp = nf_bf + (size_t)srcI[e0 + e] * 144 + (r - 18) * 8; dcol = 144 + (r - 18) * 8; }
        else             { sp = ef_buf + (size_t)(e0 + e) * 128 + (r - 36) * 8;    dcol = 288 + (r - 36) * 8; }
        *(s16x8*)&catA[e * 424 + dcol] = *(const s16x8*)sp;
    }
    __syncthreads();

    const int lane = tid & 63;
    const int wid = tid >> 6;       // 0..3 : N-slice owner
    const int lr = lane & 15;
    const int lk = lane >> 4;
    const f32x4 z4 = {0.f, 0.f, 0.f, 0.f};

    // ---- layer 1: (32 x 416) @ (416 x 256) -> out1
    f32x4 acc[2][4];
    for (int mt = 0; mt < 2; mt++)
        for (int nt = 0; nt < 4; nt++) acc[mt][nt] = z4;
    for (int kc = 0; kc < 13; kc++) {
        s16x8 a0 = *(const s16x8*)&catA[(0 + lr) * 424 + kc * 32 + lk * 8];
        s16x8 a1 = *(const s16x8*)&catA[(16 + lr) * 424 + kc * 32 + lk * 8];
#pragma unroll
        for (int nt = 0; nt < 4; nt++) {
            int nn = wid * 64 + nt * 16 + lr;
            s16x8 b = *(const s16x8*)&w1b[(size_t)nn * 416 + kc * 32 + lk * 8];
            acc[0][nt] = __builtin_amdgcn_mfma_f32_16x16x32_bf16(a0, b, acc[0][nt], 0, 0, 0);
            acc[1][nt] = __builtin_amdgcn_mfma_f32_16x16x32_bf16(a1, b, acc[1][nt], 0, 0, 0);
        }
    }
#pragma unroll
    for (int nt = 0; nt < 4; nt++) {
        int nn = wid * 64 + nt * 16 + lr;
        float bias = me_b1[nn];
#pragma unroll
        for (int mt = 0; mt < 2; mt++)
#pragma unroll
            for (int r = 0; r < 4; r++) {
                int m = mt * 16 + lk * 4 + r;
                out1[m * 264 + nn] = f2bf(fmaxf(acc[mt][nt][r] + bias, 0.f));
            }
    }
    __syncthreads();

    // ---- layer 2: (32 x 256) @ (256 x 128) -> ef_new (into catA[.,144:272] and global)
    f32x4 acc2[2][2];
    for (int mt = 0; mt < 2; mt++)
        for (int nt = 0; nt < 2; nt++) acc2[mt][nt] = z4;
    for (int kc = 0; kc < 8; kc++) {
        s16x8 a0 = *(const s16x8*)&out1[(0 + lr) * 264 + kc * 32 + lk * 8];
        s16x8 a1 = *(const s16x8*)&out1[(16 + lr) * 264 + kc * 32 + lk * 8];
#pragma unroll
        for (int nt = 0; nt < 2; nt++) {
            int nn = wid * 32 + nt * 16 + lr;
            s16x8 b = *(const s16x8*)&w2b[(size_t)nn * 256 + kc * 32 + lk * 8];
            acc2[0][nt] = __builtin_amdgcn_mfma_f32_16x16x32_bf16(a0, b, acc2[0][nt], 0, 0, 0);
            acc2[1][nt] = __builtin_amdgcn_mfma_f32_16x16x32_bf16(a1, b, acc2[1][nt], 0, 0, 0);
        }
    }
#pragma unroll
    for (int nt = 0; nt < 2; nt++) {
        int nn = wid * 32 + nt * 16 + lr;
        float bias = me_b2[nn];
#pragma unroll
        for (int mt = 0; mt < 2; mt++)
#pragma unroll
            for (int r = 0; r < 4; r++) {
                int m = mt * 16 + lk * 4 + r;
                unsigned short bb = f2bf(fmaxf(acc2[mt][nt][r] + bias, 0.f));
                catA[m * 424 + 144 + nn] = bb;
                ef_buf[(size_t)(e0 + m) * 128 + nn] = bb;
            }
    }
    __syncthreads();

    // ---- layer 3: (32 x 288) @ (288 x 128) -> msg, atomic scatter into node_acc
    f32x4 acc3[2][2];
    for (int mt = 0; mt < 2; mt++)
        for (int nt = 0; nt < 2; nt++) acc3[mt][nt] = z4;
    for (int kc = 0; kc < 9; kc++) {
        s16x8 a0 = *(const s16x8*)&catA[(0 + lr) * 424 + kc * 32 + lk * 8];
        s16x8 a1 = *(const s16x8*)&catA[(16 + lr) * 424 + kc * 32 + lk * 8];
#pragma unroll
        for (int nt = 0; nt < 2; nt++) {
            int nn = wid * 32 + nt * 16 + lr;
            s16x8 b = *(const s16x8*)&w3b[(size_t)nn * 288 + kc * 32 + lk * 8];
            acc3[0][nt] = __builtin_amdgcn_mfma_f32_16x16x32_bf16(a0, b, acc3[0][nt], 0, 0, 0);
            acc3[1][nt] = __builtin_amdgcn_mfma_f32_16x16x32_bf16(a1, b, acc3[1][nt], 0, 0, 0);
        }
    }
#pragma unroll
    for (int nt = 0; nt < 2; nt++) {
        int nn = wid * 32 + nt * 16 + lr;
        float bias = mn_b[nn];
#pragma unroll
        for (int mt = 0; mt < 2; mt++)
#pragma unroll
            for (int r = 0; r < 4; r++) {
                int m = mt * 16 + lk * 4 + r;
                float v = fmaxf(acc3[mt][nt][r] + bias, 0.f);
                atomicAdd(&node_acc[(size_t)tgt_s[m] * 128 + nn], v);
            }
    }
}

// ---------------- edge head: pe + fp32 edge_features output
__global__ __launch_bounds__(256) void k_edge_head(const unsigned short* __restrict__ ef,
                                                   const float* __restrict__ w1, const float* __restrict__ b1,
                                                   const float* __restrict__ w2, const float* __restrict__ b2,
                                                   float* __restrict__ pe, float* __restrict__ ef_out) {
    __shared__ float ws[64 * 128];
    __shared__ float w2s[64];
    __shared__ float b1s[64];
    for (int i = threadIdx.x; i < 64 * 128; i += 256) ws[i] = w1[i];
    if (threadIdx.x < 64) { w2s[threadIdx.x] = w2[threadIdx.x]; b1s[threadIdx.x] = b1[threadIdx.x]; }
    __syncthreads();
    const int e = blockIdx.x * 256 + threadIdx.x;
    float xv[128];
#pragma unroll
    for (int d8 = 0; d8 < 16; d8++) {
        s16x8 v8 = *(const s16x8*)&ef[(size_t)e * 128 + d8 * 8];
#pragma unroll
        for (int j = 0; j < 8; j++) {
            float f = bf2f((unsigned short)v8[j]);
            xv[d8 * 8 + j] = f;
            ef_out[(size_t)e * 128 + d8 * 8 + j] = f;
        }
    }
    float acc2 = b2[0];
    for (int h = 0; h < 64; h++) {
        float a = b1s[h];
        const float* wr = &ws[h * 128];
#pragma unroll 16
        for (int d = 0; d < 128; d++) a += xv[d] * wr[d];
        acc2 += w2s[h] * fmaxf(a, 0.f);
    }
    pe[e] = acc2;
}

// ---------------- node head 1: pn + fp32 node_features output
__global__ __launch_bounds__(256) void k_node_head1(const float* __restrict__ nf,
                                                    const float* __restrict__ w1, const float* __restrict__ b1,
                                                    const float* __restrict__ w2, const float* __restrict__ b2,
                                                    float* __restrict__ pn, float* __restrict__ nf_out) {
    __shared__ float ws[64 * 128];
    __shared__ float w2s[64];
    __shared__ float b1s[64];
    for (int i = threadIdx.x; i < 64 * 128; i += 256) ws[i] = w1[i];
    if (threadIdx.x < 64) { w2s[threadIdx.x] = w2[threadIdx.x]; b1s[threadIdx.x] = b1[threadIdx.x]; }
    __syncthreads();
    const int n = blockIdx.x * 256 + threadIdx.x;
    float xv[128];
#pragma unroll
    for (int d = 0; d < 128; d++) {
        float f = nf[(size_t)n * 128 + d];
        xv[d] = f;
        nf_out[(size_t)n * 128 + d] = f;
    }
    float acc2 = b2[0];
    for (int h = 0; h < 64; h++) {
        float a = b1s[h];
        const float* wr = &ws[h * 128];
#pragma unroll 16
        for (int d = 0; d < 128; d++) a += xv[d] * wr[d];
        acc2 += w2s[h] * fmaxf(a, 0.f);
    }
    pn[n] = acc2;
}

// ---------------- node head 2: pc (17 classes)
__global__ __launch_bounds__(256) void k_node_head2(const float* __restrict__ nf,
                                                    const float* __restrict__ w1, const float* __restrict__ b1,
                                                    const float* __restrict__ w2, const float* __restrict__ b2,
                                                    float* __restrict__ pc) {
    __shared__ float ws[64 * 128];
    __shared__ float w2s[17 * 64];
    __shared__ float b1s[64];
    __shared__ float b2s[17];
    for (int i = threadIdx.x; i < 64 * 128; i += 256) ws[i] = w1[i];
    for (int i = threadIdx.x; i < 17 * 64; i += 256) w2s[i] = w2[i];
    if (threadIdx.x < 64) b1s[threadIdx.x] = b1[threadIdx.x];
    if (threadIdx.x < 17) b2s[threadIdx.x] = b2[threadIdx.x];
    __syncthreads();
    const int n = blockIdx.x * 256 + threadIdx.x;
    float xv[128];
#pragma unroll
    for (int d = 0; d < 128; d++) xv[d] = nf[(size_t)n * 128 + d];
    float hr[64];
    for (int h = 0; h < 64; h++) {
        float a = b1s[h];
        const float* wr = &ws[h * 128];
#pragma unroll 16
        for (int d = 0; d < 128; d++) a += xv[d] * wr[d];
        hr[h] = fmaxf(a, 0.f);
    }
    for (int c = 0; c < 17; c++) {
        float a = b2s[c];
#pragma unroll 16
        for (int h = 0; h < 64; h++) a += w2s[c * 64 + h] * hr[h];
        pc[(size_t)n * 17 + c] = a;
    }
}

extern "C" void kernel_launch(void* const* d_in, const int* in_sizes, int n_in,
                              void* d_out, int out_size, void* d_ws, size_t ws_size,
                              hipStream_t stream) {
    const float* x         = (const float*)d_in[0];
    const float* edge_attr = (const float*)d_in[1];
    const int*   edge_idx  = (const int*)d_in[2];
    const float* fmaps     = (const float*)d_in[3];
    const int*   batch_ix  = (const int*)d_in[4];
    const float* ne_w  = (const float*)d_in[5];
    const float* ne_b  = (const float*)d_in[6];
    const float* ee_w  = (const float*)d_in[7];
    const float* ee_b  = (const float*)d_in[8];
    const float* me_w1 = (const float*)d_in[9];
    const float* me_b1 = (const float*)d_in[10];
    const float* me_w2 = (const float*)d_in[11];
    const float* me_b2 = (const float*)d_in[12];
    const float* mn_w  = (const float*)d_in[13];
    const float* mn_b  = (const float*)d_in[14];
    const float* key_w = (const float*)d_in[15];
    const float* key_b = (const float*)d_in[16];
    const float* q_w   = (const float*)d_in[17];
    const float* q_b   = (const float*)d_in[18];
    const float* v_w   = (const float*)d_in[19];
    const float* v_b   = (const float*)d_in[20];
    const float* ec_w1 = (const float*)d_in[21];
    const float* ec_b1 = (const float*)d_in[22];
    const float* ec_w2 = (const float*)d_in[23];
    const float* ec_b2 = (const float*)d_in[24];
    const float* nc_w1 = (const float*)d_in[25];
    const float* nc_b1 = (const float*)d_in[26];
    const float* nc_w2 = (const float*)d_in[27];
    const float* nc_b2 = (const float*)d_in[28];
    const float* cl_w1 = (const float*)d_in[29];
    const float* cl_b1 = (const float*)d_in[30];
    const float* cl_w2 = (const float*)d_in[31];
    const float* cl_b2 = (const float*)d_in[32];

    char* wsp = (char*)d_ws;
    size_t off = 0;
    auto alloc = [&](size_t bytes) -> void* {
        void* p = wsp + off;
        off += (bytes + 255) & ~(size_t)255;
        return p;
    };
    float* q_buf = (float*)alloc((size_t)BATCH * 16 * PPIX * sizeof(float));
    float* v_buf = (float*)alloc((size_t)BATCH * 16 * PPIX * sizeof(float));
    float* nfA   = (float*)alloc((size_t)N_NODES * 128 * sizeof(float));
    float* nfB   = (float*)alloc((size_t)N_NODES * 128 * sizeof(float));
    unsigned short* nf_bf  = (unsigned short*)alloc((size_t)N_NODES * 144 * 2);
    unsigned short* ef_buf = (unsigned short*)alloc((size_t)N_EDGES * 128 * 2);
    unsigned short* w1b = (unsigned short*)alloc(256 * 416 * 2);
    unsigned short* w2b = (unsigned short*)alloc(128 * 256 * 2);
    unsigned short* w3b = (unsigned short*)alloc(128 * 288 * 2);

    float* pe_out = (float*)d_out;
    float* pn_out = pe_out + N_EDGES;
    float* pc_out = pn_out + N_NODES;
    float* nf_out = pc_out + (size_t)N_NODES * 17;
    float* ef_out = nf_out + (size_t)N_NODES * 128;

    k_wconv<<<416, 256, 0, stream>>>(me_w1, me_w2, mn_w, w1b, w2b, w3b);
    k_node_enc<<<N_NODES, 128, 0, stream>>>(x, ne_w, ne_b, nfA);
    k_edge_enc<<<N_EDGES / 256, 256, 0, stream>>>(edge_attr, ee_w, ee_b, ef_buf);
    k_qv<<<64, 256, 0, stream>>>(fmaps, q_w, q_b, v_w, v_b, q_buf, v_buf);

    float* cur = nfA;
    float* nxt = nfB;
    for (int step = 0; step < STEPS; step++) {
        k_attn<<<N_NODES, 256, 0, stream>>>(cur, q_buf, v_buf, key_w, key_b, batch_ix, nf_bf);
        hipMemsetAsync(nxt, 0, (size_t)N_NODES * 128 * sizeof(float), stream);
        k_mlp<<<N_EDGES / 32, 256, 0, stream>>>(nf_bf, ef_buf, w1b, w2b, w3b,
                                                me_b1, me_b2, mn_b, edge_idx, nxt);
        float* tmp = cur; cur = nxt; nxt = tmp;
    }

    k_edge_head<<<N_EDGES / 256, 256, 0, stream>>>(ef_buf, ec_w1, ec_b1, ec_w2, ec_b2, pe_out, ef_out);
    k_node_head1<<<N_NODES / 256, 256, 0, stream>>>(cur, nc_w1, nc_b1, nc_w2, nc_b2, pn_out, nf_out);
    k_node_head2<<<N_NODES / 256, 256, 0, stream>>>(cur, cl_w1, cl_b1, cl_w2, cl_b2, pc_out);
}

// Round 2
// 852.486 us; speedup vs baseline: 1.8445x; 1.8445x over previous
//
#include <hip/hip_runtime.h>

// Problem constants
#define N_NODES 2048
#define N_EDGES 65536
#define BATCH   4
#define PPIX    4096   // H*W
#define STEPS   4

typedef __attribute__((ext_vector_type(4))) float f32x4;
typedef __attribute__((ext_vector_type(8))) short s16x8;

__device__ __forceinline__ unsigned short f2bf(float f) {
    unsigned u = __float_as_uint(f);
    unsigned r = u + 0x7fffu + ((u >> 16) & 1u);
    return (unsigned short)(r >> 16);
}
__device__ __forceinline__ float bf2f(unsigned short h) {
    return __uint_as_float(((unsigned)h) << 16);
}

// ---------------- weight conversion (fp32 -> bf16; mn_w zero-padded K 272->288; ec_w1 added)
__global__ void k_wconv(const float* __restrict__ w1, const float* __restrict__ w2,
                        const float* __restrict__ w3, const float* __restrict__ ec1,
                        unsigned short* __restrict__ o1, unsigned short* __restrict__ o2,
                        unsigned short* __restrict__ o3, unsigned short* __restrict__ o4) {
    int i = blockIdx.x * 256 + threadIdx.x;
    if (i < 256 * 416) o1[i] = f2bf(w1[i]);
    if (i < 128 * 256) o2[i] = f2bf(w2[i]);
    if (i < 128 * 288) {
        int r = i / 288, c = i - r * 288;
        o3[i] = (c < 272) ? f2bf(w3[r * 272 + c]) : (unsigned short)0;
    }
    if (i < 64 * 128) o4[i] = f2bf(ec1[i]);
}

// ---------------- node encoder: relu(x @ ne_w.T + ne_b) -> (2048,128) fp32
__global__ __launch_bounds__(128) void k_node_enc(const float* __restrict__ x,
                                                  const float* __restrict__ w,
                                                  const float* __restrict__ b,
                                                  float* __restrict__ out) {
    __shared__ float xs[256];
    const int n = blockIdx.x;
    for (int i = threadIdx.x; i < 256; i += 128) xs[i] = x[n * 256 + i];
    __syncthreads();
    const int d = threadIdx.x;
    const float* wr = w + d * 256;
    float acc = b[d];
#pragma unroll 8
    for (int c = 0; c < 256; c++) acc += xs[c] * wr[c];
    out[n * 128 + d] = fmaxf(acc, 0.f);
}

// ---------------- edge encoder: relu(edge_attr @ ee_w.T + ee_b) -> (65536,128) bf16
__global__ __launch_bounds__(256) void k_edge_enc(const float* __restrict__ ea,
                                                  const float* __restrict__ w,
                                                  const float* __restrict__ b,
                                                  unsigned short* __restrict__ ef) {
    __shared__ float ws[128 * 64];
    __shared__ float bs[128];
    for (int i = threadIdx.x; i < 128 * 64; i += 256) ws[i] = w[i];
    if (threadIdx.x < 128) bs[threadIdx.x] = b[threadIdx.x];
    __syncthreads();
    const int e = blockIdx.x * 256 + threadIdx.x;
    float xr[64];
#pragma unroll
    for (int c = 0; c < 64; c++) xr[c] = ea[(size_t)e * 64 + c];
    for (int d = 0; d < 128; d++) {
        float acc = bs[d];
        const float* wr = &ws[d * 64];
#pragma unroll
        for (int c = 0; c < 64; c++) acc += xr[c] * wr[c];
        ef[(size_t)e * 128 + d] = f2bf(fmaxf(acc, 0.f));
    }
}

// ---------------- queries/values: einsum('oc,bcp->bop') + bias
__global__ __launch_bounds__(256) void k_qv(const float* __restrict__ fm,
                                            const float* __restrict__ qw, const float* __restrict__ qb,
                                            const float* __restrict__ vw, const float* __restrict__ vb,
                                            float* __restrict__ q, float* __restrict__ v) {
    __shared__ float fs[32][256];
    const int b = blockIdx.x >> 4;
    const int pt = blockIdx.x & 15;
    for (int i = threadIdx.x; i < 32 * 256; i += 256) {
        int c = i >> 8, p = i & 255;
        fs[c][p] = fm[(size_t)b * 32 * PPIX + (size_t)c * PPIX + pt * 256 + p];
    }
    __syncthreads();
    const int p = threadIdx.x;
    for (int o = 0; o < 16; o++) {
        float qa = qb[o], va = vb[o];
#pragma unroll
        for (int c = 0; c < 32; c++) {
            float f = fs[c][p];
            qa += qw[o * 32 + c] * f;
            va += vw[o * 32 + c] * f;
        }
        size_t oidx = ((size_t)b * 16 + o) * PPIX + pt * 256 + p;
        q[oidx] = qa;
        v[oidx] = va;
    }
}

// ---------------- attention per node (fused k-proj, softmax over p, res, nf_bf16 pack)
__global__ __launch_bounds__(256) void k_attn(const float* __restrict__ nf,
                                              const float* __restrict__ qbuf,
                                              const float* __restrict__ vbuf,
                                              const float* __restrict__ key_w,
                                              const float* __restrict__ key_b,
                                              const int* __restrict__ batch_index,
                                              unsigned short* __restrict__ nf_bf) {
    __shared__ float xs[128];
    __shared__ float k16s[16];
    __shared__ float red[256];
    __shared__ float vr[256 * 17];
    const int n = blockIdx.x;
    const int t = threadIdx.x;
    if (t < 128) xs[t] = nf[n * 128 + t];
    __syncthreads();
    if (t < 16) {
        const float* wr = key_w + t * 128;
        float a = key_b[t];
        for (int c = 0; c < 128; c++) a += xs[c] * wr[c];
        k16s[t] = a;
    }
    __syncthreads();
    float kk[16];
#pragma unroll
    for (int a = 0; a < 16; a++) kk[a] = k16s[a];
    const int b = batch_index[n];
    const float* q = qbuf + (size_t)b * 16 * PPIX;
    const float* v = vbuf + (size_t)b * 16 * PPIX;

    float s[16];
    float mx = -1e30f;
    for (int i = 0; i < 16; i++) {
        int p = i * 256 + t;
        float acc = 0.f;
#pragma unroll
        for (int a = 0; a < 16; a++) acc += kk[a] * q[a * PPIX + p];
        s[i] = acc;
        mx = fmaxf(mx, acc);
    }
    red[t] = mx;
    __syncthreads();
    for (int off = 128; off > 0; off >>= 1) {
        if (t < off) red[t] = fmaxf(red[t], red[t + off]);
        __syncthreads();
    }
    mx = red[0];
    __syncthreads();

    float wsum = 0.f;
    float vacc[16];
#pragma unroll
    for (int a = 0; a < 16; a++) vacc[a] = 0.f;
    for (int i = 0; i < 16; i++) {
        int p = i * 256 + t;
        float w = __expf(s[i] - mx);
        wsum += w;
#pragma unroll
        for (int a = 0; a < 16; a++) vacc[a] += w * v[a * PPIX + p];
    }
    red[t] = wsum;
    __syncthreads();
    for (int off = 128; off > 0; off >>= 1) {
        if (t < off) red[t] += red[t + off];
        __syncthreads();
    }
    wsum = red[0];
    __syncthreads();

#pragma unroll
    for (int a = 0; a < 16; a++) vr[t * 17 + a] = vacc[a];
    __syncthreads();
    for (int off = 128; off > 0; off >>= 1) {
        if (t < off) {
#pragma unroll
            for (int a = 0; a < 16; a++) vr[t * 17 + a] += vr[(t + off) * 17 + a];
        }
        __syncthreads();
    }
    if (t < 128) nf_bf[n * 144 + t] = f2bf(xs[t]);
    if (t < 16) {
        float rv = vr[t] / wsum;
        nf_bf[n * 144 + 128 + t] = f2bf(rv);
    }
}

// ---------------- fused 3-layer edge MLP + message scatter (bf16 MFMA)
// tile = 32 edges, 256 threads (4 waves), waves split the N dimension.
__global__ __launch_bounds__(256) void k_mlp(const unsigned short* __restrict__ nf_bf,
                                             unsigned short* __restrict__ ef_buf,
                                             const unsigned short* __restrict__ w1b,
                                             const unsigned short* __restrict__ w2b,
                                             const unsigned short* __restrict__ w3b,
                                             const float* __restrict__ me_b1,
                                             const float* __restrict__ me_b2,
                                             const float* __restrict__ mn_b,
                                             const int* __restrict__ ei,
                                             float* __restrict__ node_acc) {
    __shared__ __attribute__((aligned(16))) unsigned short catA[32 * 424]; // [x_i 0:144 | x_j 144:288 | ef 288:416 | pad]
    __shared__ __attribute__((aligned(16))) unsigned short out1[32 * 264];
    __shared__ int tgt_s[32];
    const int tid = threadIdx.x;
    const int e0 = blockIdx.x * 32;
    const int* srcI = ei;
    const int* tgtI = ei + N_EDGES;
    if (tid < 32) tgt_s[tid] = tgtI[e0 + tid];
    // gather staging: 52 x 16B chunks per edge
    for (int c = tid; c < 32 * 52; c += 256) {
        int e = c / 52;
        int r = c - e * 52;
        const unsigned short* sp;
        int dcol;
        if (r < 18)      { sp = nf_bf + (size_t)tgtI[e0 + e] * 144 + r * 8;        dcol = r * 8; }
        else if (r < 36) { sp = nf_bf + (size_t)srcI[e0 + e] * 144 + (r - 18) * 8; dcol = 144 + (r - 18) * 8; }
        else             { sp = ef_buf + (size_t)(e0 + e) * 128 + (r - 36) * 8;    dcol = 288 + (r - 36) * 8; }
        *(s16x8*)&catA[e * 424 + dcol] = *(const s16x8*)sp;
    }
    __syncthreads();

    const int lane = tid & 63;
    const int wid = tid >> 6;       // 0..3 : N-slice owner
    const int lr = lane & 15;
    const int lk = lane >> 4;
    const f32x4 z4 = {0.f, 0.f, 0.f, 0.f};

    // ---- layer 1: (32 x 416) @ (416 x 256) -> out1
    f32x4 acc[2][4];
    for (int mt = 0; mt < 2; mt++)
        for (int nt = 0; nt < 4; nt++) acc[mt][nt] = z4;
    for (int kc = 0; kc < 13; kc++) {
        s16x8 a0 = *(const s16x8*)&catA[(0 + lr) * 424 + kc * 32 + lk * 8];
        s16x8 a1 = *(const s16x8*)&catA[(16 + lr) * 424 + kc * 32 + lk * 8];
#pragma unroll
        for (int nt = 0; nt < 4; nt++) {
            int nn = wid * 64 + nt * 16 + lr;
            s16x8 b = *(const s16x8*)&w1b[(size_t)nn * 416 + kc * 32 + lk * 8];
            acc[0][nt] = __builtin_amdgcn_mfma_f32_16x16x32_bf16(a0, b, acc[0][nt], 0, 0, 0);
            acc[1][nt] = __builtin_amdgcn_mfma_f32_16x16x32_bf16(a1, b, acc[1][nt], 0, 0, 0);
        }
    }
#pragma unroll
    for (int nt = 0; nt < 4; nt++) {
        int nn = wid * 64 + nt * 16 + lr;
        float bias = me_b1[nn];
#pragma unroll
        for (int mt = 0; mt < 2; mt++)
#pragma unroll
            for (int r = 0; r < 4; r++) {
                int m = mt * 16 + lk * 4 + r;
                out1[m * 264 + nn] = f2bf(fmaxf(acc[mt][nt][r] + bias, 0.f));
            }
    }
    __syncthreads();

    // ---- layer 2: (32 x 256) @ (256 x 128) -> ef_new (into catA[.,144:272] and global)
    f32x4 acc2[2][2];
    for (int mt = 0; mt < 2; mt++)
        for (int nt = 0; nt < 2; nt++) acc2[mt][nt] = z4;
    for (int kc = 0; kc < 8; kc++) {
        s16x8 a0 = *(const s16x8*)&out1[(0 + lr) * 264 + kc * 32 + lk * 8];
        s16x8 a1 = *(const s16x8*)&out1[(16 + lr) * 264 + kc * 32 + lk * 8];
#pragma unroll
        for (int nt = 0; nt < 2; nt++) {
            int nn = wid * 32 + nt * 16 + lr;
            s16x8 b = *(const s16x8*)&w2b[(size_t)nn * 256 + kc * 32 + lk * 8];
            acc2[0][nt] = __builtin_amdgcn_mfma_f32_16x16x32_bf16(a0, b, acc2[0][nt], 0, 0, 0);
            acc2[1][nt] = __builtin_amdgcn_mfma_f32_16x16x32_bf16(a1, b, acc2[1][nt], 0, 0, 0);
        }
    }
#pragma unroll
    for (int nt = 0; nt < 2; nt++) {
        int nn = wid * 32 + nt * 16 + lr;
        float bias = me_b2[nn];
#pragma unroll
        for (int mt = 0; mt < 2; mt++)
#pragma unroll
            for (int r = 0; r < 4; r++) {
                int m = mt * 16 + lk * 4 + r;
                unsigned short bb = f2bf(fmaxf(acc2[mt][nt][r] + bias, 0.f));
                catA[m * 424 + 144 + nn] = bb;
                ef_buf[(size_t)(e0 + m) * 128 + nn] = bb;
            }
    }
    __syncthreads();

    // ---- layer 3: (32 x 288) @ (288 x 128) -> msg, atomic scatter into node_acc
    f32x4 acc3[2][2];
    for (int mt = 0; mt < 2; mt++)
        for (int nt = 0; nt < 2; nt++) acc3[mt][nt] = z4;
    for (int kc = 0; kc < 9; kc++) {
        s16x8 a0 = *(const s16x8*)&catA[(0 + lr) * 424 + kc * 32 + lk * 8];
        s16x8 a1 = *(const s16x8*)&catA[(16 + lr) * 424 + kc * 32 + lk * 8];
#pragma unroll
        for (int nt = 0; nt < 2; nt++) {
            int nn = wid * 32 + nt * 16 + lr;
            s16x8 b = *(const s16x8*)&w3b[(size_t)nn * 288 + kc * 32 + lk * 8];
            acc3[0][nt] = __builtin_amdgcn_mfma_f32_16x16x32_bf16(a0, b, acc3[0][nt], 0, 0, 0);
            acc3[1][nt] = __builtin_amdgcn_mfma_f32_16x16x32_bf16(a1, b, acc3[1][nt], 0, 0, 0);
        }
    }
#pragma unroll
    for (int nt = 0; nt < 2; nt++) {
        int nn = wid * 32 + nt * 16 + lr;
        float bias = mn_b[nn];
#pragma unroll
        for (int mt = 0; mt < 2; mt++)
#pragma unroll
            for (int r = 0; r < 4; r++) {
                int m = mt * 16 + lk * 4 + r;
                float v = fmaxf(acc3[mt][nt][r] + bias, 0.f);
                atomicAdd(&node_acc[(size_t)tgt_s[m] * 128 + nn], v);
            }
    }
}

// ---------------- edge head (MFMA): pe + fp32 edge_features output
// 32 edges/block; layer1 (32x128)@(128x64) via MFMA, then 64->1 dot per edge.
__global__ __launch_bounds__(256) void k_edge_head(const unsigned short* __restrict__ ef,
                                                   const unsigned short* __restrict__ w1b,
                                                   const float* __restrict__ b1,
                                                   const float* __restrict__ w2,
                                                   const float* __restrict__ b2,
                                                   float* __restrict__ pe,
                                                   float* __restrict__ ef_out) {
    __shared__ __attribute__((aligned(16))) unsigned short efs[32][136];
    __shared__ float h_s[32][68];
    const int tid = threadIdx.x;
    const int e0 = blockIdx.x * 32;
    // stage 32x128 bf16 tile + write fp32 ef_out
    for (int c = tid; c < 32 * 16; c += 256) {
        int e = c >> 4, r = c & 15;
        s16x8 v = *(const s16x8*)&ef[(size_t)(e0 + e) * 128 + r * 8];
        *(s16x8*)&efs[e][r * 8] = v;
        float4 lo, hi;
        lo.x = bf2f((unsigned short)v[0]); lo.y = bf2f((unsigned short)v[1]);
        lo.z = bf2f((unsigned short)v[2]); lo.w = bf2f((unsigned short)v[3]);
        hi.x = bf2f((unsigned short)v[4]); hi.y = bf2f((unsigned short)v[5]);
        hi.z = bf2f((unsigned short)v[6]); hi.w = bf2f((unsigned short)v[7]);
        size_t ob = (size_t)(e0 + e) * 128 + r * 8;
        *(float4*)&ef_out[ob] = lo;
        *(float4*)&ef_out[ob + 4] = hi;
    }
    __syncthreads();
    const int lane = tid & 63;
    const int wid = tid >> 6;   // owns h block wid*16
    const int lr = lane & 15;
    const int lk = lane >> 4;
    const f32x4 z4 = {0.f, 0.f, 0.f, 0.f};
    f32x4 acc0 = z4, acc1 = z4;
    for (int kc = 0; kc < 4; kc++) {
        s16x8 a0 = *(const s16x8*)&efs[lr][kc * 32 + lk * 8];
        s16x8 a1 = *(const s16x8*)&efs[16 + lr][kc * 32 + lk * 8];
        s16x8 b = *(const s16x8*)&w1b[(size_t)(wid * 16 + lr) * 128 + kc * 32 + lk * 8];
        acc0 = __builtin_amdgcn_mfma_f32_16x16x32_bf16(a0, b, acc0, 0, 0, 0);
        acc1 = __builtin_amdgcn_mfma_f32_16x16x32_bf16(a1, b, acc1, 0, 0, 0);
    }
    {
        int h = wid * 16 + lr;
        float bias = b1[h];
#pragma unroll
        for (int r = 0; r < 4; r++) {
            h_s[lk * 4 + r][h]      = fmaxf(acc0[r] + bias, 0.f);
            h_s[16 + lk * 4 + r][h] = fmaxf(acc1[r] + bias, 0.f);
        }
    }
    __syncthreads();
    if (tid < 32) {
        float a = b2[0];
#pragma unroll 8
        for (int h = 0; h < 64; h++) a += w2[h] * h_s[tid][h];
        pe[e0 + tid] = a;
    }
}

// ---------------- fused node heads: pn, pc, nf_out. One wave per node.
__global__ __launch_bounds__(64) void k_node_heads(const float* __restrict__ nf,
                                                   const float* __restrict__ nc_w1, const float* __restrict__ nc_b1,
                                                   const float* __restrict__ nc_w2, const float* __restrict__ nc_b2,
                                                   const float* __restrict__ cl_w1, const float* __restrict__ cl_b1,
                                                   const float* __restrict__ cl_w2, const float* __restrict__ cl_b2,
                                                   float* __restrict__ pn, float* __restrict__ pc,
                                                   float* __restrict__ nf_out) {
    __shared__ float xs[128];
    __shared__ float hr2[64];
    const int n = blockIdx.x;
    const int t = threadIdx.x;
    float2 xv = *(const float2*)&nf[(size_t)n * 128 + t * 2];
    xs[t * 2] = xv.x;
    xs[t * 2 + 1] = xv.y;
    *(float2*)&nf_out[(size_t)n * 128 + t * 2] = xv;
    __syncthreads();
    float a1 = nc_b1[t], a2 = cl_b1[t];
#pragma unroll 8
    for (int d4 = 0; d4 < 32; d4++) {
        float4 w1v = *(const float4*)&nc_w1[(size_t)t * 128 + d4 * 4];
        float4 w2v = *(const float4*)&cl_w1[(size_t)t * 128 + d4 * 4];
        float x0 = xs[d4 * 4], x1 = xs[d4 * 4 + 1], x2 = xs[d4 * 4 + 2], x3 = xs[d4 * 4 + 3];
        a1 += x0 * w1v.x + x1 * w1v.y + x2 * w1v.z + x3 * w1v.w;
        a2 += x0 * w2v.x + x1 * w2v.y + x2 * w2v.z + x3 * w2v.w;
    }
    float h1 = fmaxf(a1, 0.f);
    hr2[t] = fmaxf(a2, 0.f);
    float p = nc_w2[t] * h1;
#pragma unroll
    for (int off = 32; off > 0; off >>= 1) p += __shfl_down(p, off);
    if (t == 0) pn[n] = p + nc_b2[0];
    __syncthreads();
    if (t < 17) {
        float a = cl_b2[t];
#pragma unroll 8
        for (int h = 0; h < 64; h++) a += cl_w2[t * 64 + h] * hr2[h];
        pc[(size_t)n * 17 + t] = a;
    }
}

extern "C" void kernel_launch(void* const* d_in, const int* in_sizes, int n_in,
                              void* d_out, int out_size, void* d_ws, size_t ws_size,
                              hipStream_t stream) {
    const float* x         = (const float*)d_in[0];
    const float* edge_attr = (const float*)d_in[1];
    const int*   edge_idx  = (const int*)d_in[2];
    const float* fmaps     = (const float*)d_in[3];
    const int*   batch_ix  = (const int*)d_in[4];
    const float* ne_w  = (const float*)d_in[5];
    const float* ne_b  = (const float*)d_in[6];
    const float* ee_w  = (const float*)d_in[7];
    const float* ee_b  = (const float*)d_in[8];
    const float* me_w1 = (const float*)d_in[9];
    const float* me_b1 = (const float*)d_in[10];
    const float* me_w2 = (const float*)d_in[11];
    const float* me_b2 = (const float*)d_in[12];
    const float* mn_w  = (const float*)d_in[13];
    const float* mn_b  = (const float*)d_in[14];
    const float* key_w = (const float*)d_in[15];
    const float* key_b = (const float*)d_in[16];
    const float* q_w   = (const float*)d_in[17];
    const float* q_b   = (const float*)d_in[18];
    const float* v_w   = (const float*)d_in[19];
    const float* v_b   = (const float*)d_in[20];
    const float* ec_w1 = (const float*)d_in[21];
    const float* ec_b1 = (const float*)d_in[22];
    const float* ec_w2 = (const float*)d_in[23];
    const float* ec_b2 = (const float*)d_in[24];
    const float* nc_w1 = (const float*)d_in[25];
    const float* nc_b1 = (const float*)d_in[26];
    const float* nc_w2 = (const float*)d_in[27];
    const float* nc_b2 = (const float*)d_in[28];
    const float* cl_w1 = (const float*)d_in[29];
    const float* cl_b1 = (const float*)d_in[30];
    const float* cl_w2 = (const float*)d_in[31];
    const float* cl_b2 = (const float*)d_in[32];

    char* wsp = (char*)d_ws;
    size_t off = 0;
    auto alloc = [&](size_t bytes) -> void* {
        void* p = wsp + off;
        off += (bytes + 255) & ~(size_t)255;
        return p;
    };
    float* q_buf = (float*)alloc((size_t)BATCH * 16 * PPIX * sizeof(float));
    float* v_buf = (float*)alloc((size_t)BATCH * 16 * PPIX * sizeof(float));
    float* nfA   = (float*)alloc((size_t)N_NODES * 128 * sizeof(float));
    float* nfB   = (float*)alloc((size_t)N_NODES * 128 * sizeof(float));
    unsigned short* nf_bf  = (unsigned short*)alloc((size_t)N_NODES * 144 * 2);
    unsigned short* ef_buf = (unsigned short*)alloc((size_t)N_EDGES * 128 * 2);
    unsigned short* w1b = (unsigned short*)alloc(256 * 416 * 2);
    unsigned short* w2b = (unsigned short*)alloc(128 * 256 * 2);
    unsigned short* w3b = (unsigned short*)alloc(128 * 288 * 2);
    unsigned short* w4b = (unsigned short*)alloc(64 * 128 * 2);

    float* pe_out = (float*)d_out;
    float* pn_out = pe_out + N_EDGES;
    float* pc_out = pn_out + N_NODES;
    float* nf_out = pc_out + (size_t)N_NODES * 17;
    float* ef_out = nf_out + (size_t)N_NODES * 128;

    k_wconv<<<416, 256, 0, stream>>>(me_w1, me_w2, mn_w, ec_w1, w1b, w2b, w3b, w4b);
    k_node_enc<<<N_NODES, 128, 0, stream>>>(x, ne_w, ne_b, nfA);
    k_edge_enc<<<N_EDGES / 256, 256, 0, stream>>>(edge_attr, ee_w, ee_b, ef_buf);
    k_qv<<<64, 256, 0, stream>>>(fmaps, q_w, q_b, v_w, v_b, q_buf, v_buf);

    float* cur = nfA;
    float* nxt = nfB;
    for (int step = 0; step < STEPS; step++) {
        k_attn<<<N_NODES, 256, 0, stream>>>(cur, q_buf, v_buf, key_w, key_b, batch_ix, nf_bf);
        hipMemsetAsync(nxt, 0, (size_t)N_NODES * 128 * sizeof(float), stream);
        k_mlp<<<N_EDGES / 32, 256, 0, stream>>>(nf_bf, ef_buf, w1b, w2b, w3b,
                                                me_b1, me_b2, mn_b, edge_idx, nxt);
        float* tmp = cur; cur = nxt; nxt = tmp;
    }

    k_edge_head<<<N_EDGES / 32, 256, 0, stream>>>(ef_buf, w4b, ec_b1, ec_w2, ec_b2, pe_out, ef_out);
    k_node_heads<<<N_NODES, 64, 0, stream>>>(cur, nc_w1, nc_b1, nc_w2, nc_b2,
                                             cl_w1, cl_b1, cl_w2, cl_b2, pn_out, pc_out, nf_out);
}